// Round 4
// baseline (101.765 us; speedup 1.0000x reference)
//
#include <hip/hip_runtime.h>
#include <hip/hip_bf16.h>

#define N 8192
#define D 512
#define BT 256          // tile: BM = BN = 256
#define BK 64
#define NCB (N / BT)    // 32 column blocks
#define NKT (D / BK)    // 8 K tiles
#define NTRI (NCB * (NCB + 1) / 2)  // 528 upper-triangle blocks
#define INVT 14.285714285714286f

typedef __attribute__((ext_vector_type(8))) short bf16x8;
typedef __attribute__((ext_vector_type(4))) float f32x4;
typedef __attribute__((ext_vector_type(8))) unsigned short u16x8;

__device__ __forceinline__ unsigned short f2bf(float f) {
  __hip_bfloat16 h = __float2bfloat16(f);
  return *reinterpret_cast<unsigned short*>(&h);
}

// ---------------- kernel 1: L2-normalize rows, cast to bf16 ----------------
__global__ __launch_bounds__(256) void k_normalize(const float* __restrict__ x,
                                                   unsigned short* __restrict__ fb) {
  const int row = blockIdx.x * 4 + (threadIdx.x >> 6);
  const int lane = threadIdx.x & 63;
  const float* rp = x + (size_t)row * D + lane * 8;
  float4 v0 = *reinterpret_cast<const float4*>(rp);
  float4 v1 = *reinterpret_cast<const float4*>(rp + 4);
  float s = v0.x*v0.x + v0.y*v0.y + v0.z*v0.z + v0.w*v0.w
          + v1.x*v1.x + v1.y*v1.y + v1.z*v1.z + v1.w*v1.w;
  #pragma unroll
  for (int m = 1; m < 64; m <<= 1) s += __shfl_xor(s, m);
  float inv = 1.0f / fmaxf(sqrtf(s), 1e-12f);
  u16x8 o;
  o[0] = f2bf(v0.x*inv); o[1] = f2bf(v0.y*inv); o[2] = f2bf(v0.z*inv); o[3] = f2bf(v0.w*inv);
  o[4] = f2bf(v1.x*inv); o[5] = f2bf(v1.y*inv); o[6] = f2bf(v1.z*inv); o[7] = f2bf(v1.w*inv);
  *reinterpret_cast<u16x8*>(fb + (size_t)row * D + lane * 8) = o;
}

// ---------------- kernel 2: label histogram (pos counts) ----------------
__global__ __launch_bounds__(256) void k_hist(const int* __restrict__ labels,
                                              int* __restrict__ hist) {
  __shared__ int h[128];
  int tid = threadIdx.x;
  if (tid < 128) h[tid] = 0;
  __syncthreads();
  int i = blockIdx.x * 256 + tid;
  atomicAdd(&h[labels[i]], 1);
  __syncthreads();
  if (tid < 128 && h[tid]) atomicAdd(&hist[tid], h[tid]);
}

// ---------------- kernel 3: 8-phase 256^2 fused GEMM + exp/mask reductions ----
// Upper-triangle block t -> (bx, by), by <= bx. Off-diagonal blocks emit row-
// partials (rows of by-block) AND col-partials (rows of bx-block, symmetry).
// 8 waves (2M x 4N), per-wave 128x64 output, acc[8][4]. 128 KiB LDS:
// A[2buf][2half][128][64] | B[2buf][2half][128][64], halves = 128 rows.
// Schedule per iter (2 K-tiles ka=buf0, kb=buf1), phases P1..P8:
//   P1 rd A(m0-3)+B(n0-1) buf0, stage kb.A0->buf1 | P2 rd B(n2-3), stage kb.A1
//   P3 rd A(m4-7), stage kn.B0->buf0              | P4 stage kn.B1, GATE vmcnt(4)
//   P5..P8 mirror on buf1, stages kn.A0,kn.A1,kn2.B0,kn2.B1, GATE vmcnt(4)
// WAR-safe: B halves free after P2/P6, A halves after P3/P7; every stage is
// issued >=1 phase after its target's last-read barrier. Gates guarantee the
// 4 oldest of 6 outstanding halves (8 of 12 loads) are complete = exactly the
// halves the next phase-group reads. Last iter: stages skipped, P4 gate=vmcnt(0).
#define GLOAD_LDS16(g, l) __builtin_amdgcn_global_load_lds( \
    (const __attribute__((address_space(1))) unsigned int*)(g), \
    (__attribute__((address_space(3))) unsigned int*)(l), 16, 0, 0)

__global__ __launch_bounds__(512, 2) void k_gemm(
    const unsigned short* __restrict__ fb, const int* __restrict__ labels,
    float* __restrict__ part_e, float* __restrict__ part_p) {
  __shared__ __align__(16) short lds[65536];   // 128 KiB

  const int tid = threadIdx.x;
  const int lane = tid & 63;
  const int w = tid >> 6;
  const int wm = w >> 2, wn = w & 3;
  const int l15 = lane & 15;

  const int t = blockIdx.x;
  int bx = (int)((sqrtf(8.0f * (float)t + 1.0f) - 1.0f) * 0.5f);
  while ((bx + 1) * (bx + 2) / 2 <= t) ++bx;
  while (bx * (bx + 1) / 2 > t) --bx;
  const int by = t - bx * (bx + 1) / 2;
  const bool offdiag = (bx != by);
  const int rowA0 = by * BT, rowB0 = bx * BT;

  short* As = lds;            // [buf*2+half]*8192 shorts
  short* Bs = lds + 32768;

  f32x4 acc[8][4] = {};

#define STAGE(row0, kt, DST) do { if ((kt) < NKT) { \
    _Pragma("unroll") \
    for (int it = 0; it < 2; ++it) { \
      int idx = it * 512 + tid; int r = idx >> 3; \
      int kcol = (kt) * BK + (((tid & 7) ^ (r & 7)) << 3); \
      GLOAD_LDS16(fb + (size_t)((row0) + r) * D + kcol, \
                  (char*)(DST) + it * 8192 + w * 1024); } } } while (0)

#define RD_A(dst, base, mloc, ks) do { \
    int _r = (mloc) * 16 + l15; \
    int _kb = ((((ks) * 32 + ((lane >> 4) << 3)) << 1)) ^ ((_r & 7) << 4); \
    dst = *reinterpret_cast<const bf16x8*>((const char*)(base) + _r * 128 + _kb); } while (0)

#define RD_B(dst, base, nloc, ks) do { \
    int _r = ((wn & 1) << 6) + (nloc) * 16 + l15; \
    int _kb = ((((ks) * 32 + ((lane >> 4) << 3)) << 1)) ^ ((_r & 7) << 4); \
    dst = *reinterpret_cast<const bf16x8*>((const char*)(base) + _r * 128 + _kb); } while (0)

#define MFMA16(MB, NB, FA, FB) \
    _Pragma("unroll") for (int ks = 0; ks < 2; ++ks) \
    _Pragma("unroll") for (int mm = 0; mm < 4; ++mm) \
    _Pragma("unroll") for (int nn = 0; nn < 2; ++nn) \
      acc[(MB) + mm][(NB) + nn] = __builtin_amdgcn_mfma_f32_16x16x32_bf16( \
          FA[mm][ks], FB[nn][ks], acc[(MB) + mm][(NB) + nn], 0, 0, 0)

#define PHASE_MID do { __builtin_amdgcn_s_barrier(); \
    asm volatile("s_waitcnt lgkmcnt(0)" ::: "memory"); \
    __builtin_amdgcn_sched_barrier(0); \
    __builtin_amdgcn_s_setprio(1); } while (0)
#define PHASE_END do { __builtin_amdgcn_s_setprio(0); \
    __builtin_amdgcn_s_barrier(); } while (0)
#define PHASE_END_V4 do { __builtin_amdgcn_s_setprio(0); \
    asm volatile("s_waitcnt vmcnt(4)" ::: "memory"); \
    __builtin_amdgcn_s_barrier(); } while (0)
#define PHASE_END_V0 do { __builtin_amdgcn_s_setprio(0); \
    asm volatile("s_waitcnt vmcnt(0)" ::: "memory"); \
    __builtin_amdgcn_s_barrier(); } while (0)

  const short* Ar0 = As + (0 + wm) * 8192;        // buf0 A-half[wm]
  const short* Ar1 = As + (2 + wm) * 8192;        // buf1
  const short* Br0 = Bs + (0 + (wn >> 1)) * 8192; // buf0 B-half[wn>>1]
  const short* Br1 = Bs + (2 + (wn >> 1)) * 8192; // buf1

  // ---- prologue: K0 -> buf0 (B0,B1,A0,A1), K1.B -> buf1 ----
  STAGE(rowB0 +   0, 0, Bs + 0 * 8192);
  STAGE(rowB0 + 128, 0, Bs + 1 * 8192);
  STAGE(rowA0 +   0, 0, As + 0 * 8192);
  STAGE(rowA0 + 128, 0, As + 1 * 8192);
  STAGE(rowB0 +   0, 1, Bs + 2 * 8192);
  STAGE(rowB0 + 128, 1, Bs + 3 * 8192);
  asm volatile("s_waitcnt vmcnt(4)" ::: "memory");
  __builtin_amdgcn_s_barrier();

  bf16x8 fa[4][2], fb0[2][2], fb2[2][2];

  for (int i = 0; i < NKT / 2; ++i) {
    const int kb  = 2 * i + 1;
    const int kn  = 2 * i + 2;
    const int kn2 = 2 * i + 3;
    // ---- P1
    RD_A(fa[0][0], Ar0, 0, 0); RD_A(fa[0][1], Ar0, 0, 1);
    RD_A(fa[1][0], Ar0, 1, 0); RD_A(fa[1][1], Ar0, 1, 1);
    RD_A(fa[2][0], Ar0, 2, 0); RD_A(fa[2][1], Ar0, 2, 1);
    RD_A(fa[3][0], Ar0, 3, 0); RD_A(fa[3][1], Ar0, 3, 1);
    RD_B(fb0[0][0], Br0, 0, 0); RD_B(fb0[0][1], Br0, 0, 1);
    RD_B(fb0[1][0], Br0, 1, 0); RD_B(fb0[1][1], Br0, 1, 1);
    STAGE(rowA0 +   0, kb, As + 2 * 8192);
    PHASE_MID; MFMA16(0, 0, fa, fb0); PHASE_END;
    // ---- P2
    RD_B(fb2[0][0], Br0, 2, 0); RD_B(fb2[0][1], Br0, 2, 1);
    RD_B(fb2[1][0], Br0, 3, 0); RD_B(fb2[1][1], Br0, 3, 1);
    STAGE(rowA0 + 128, kb, As + 3 * 8192);
    PHASE_MID; MFMA16(0, 2, fa, fb2); PHASE_END;
    // ---- P3
    RD_A(fa[0][0], Ar0, 4, 0); RD_A(fa[0][1], Ar0, 4, 1);
    RD_A(fa[1][0], Ar0, 5, 0); RD_A(fa[1][1], Ar0, 5, 1);
    RD_A(fa[2][0], Ar0, 6, 0); RD_A(fa[2][1], Ar0, 6, 1);
    RD_A(fa[3][0], Ar0, 7, 0); RD_A(fa[3][1], Ar0, 7, 1);
    STAGE(rowB0 +   0, kn, Bs + 0 * 8192);
    PHASE_MID; MFMA16(4, 0, fa, fb0); PHASE_END;
    // ---- P4 (gate)
    STAGE(rowB0 + 128, kn, Bs + 1 * 8192);
    PHASE_MID; MFMA16(4, 2, fa, fb2);
    if (i < NKT / 2 - 1) { PHASE_END_V4; } else { PHASE_END_V0; }
    // ---- P5
    RD_A(fa[0][0], Ar1, 0, 0); RD_A(fa[0][1], Ar1, 0, 1);
    RD_A(fa[1][0], Ar1, 1, 0); RD_A(fa[1][1], Ar1, 1, 1);
    RD_A(fa[2][0], Ar1, 2, 0); RD_A(fa[2][1], Ar1, 2, 1);
    RD_A(fa[3][0], Ar1, 3, 0); RD_A(fa[3][1], Ar1, 3, 1);
    RD_B(fb0[0][0], Br1, 0, 0); RD_B(fb0[0][1], Br1, 0, 1);
    RD_B(fb0[1][0], Br1, 1, 0); RD_B(fb0[1][1], Br1, 1, 1);
    STAGE(rowA0 +   0, kn, As + 0 * 8192);
    PHASE_MID; MFMA16(0, 0, fa, fb0); PHASE_END;
    // ---- P6
    RD_B(fb2[0][0], Br1, 2, 0); RD_B(fb2[0][1], Br1, 2, 1);
    RD_B(fb2[1][0], Br1, 3, 0); RD_B(fb2[1][1], Br1, 3, 1);
    STAGE(rowA0 + 128, kn, As + 1 * 8192);
    PHASE_MID; MFMA16(0, 2, fa, fb2); PHASE_END;
    // ---- P7
    RD_A(fa[0][0], Ar1, 4, 0); RD_A(fa[0][1], Ar1, 4, 1);
    RD_A(fa[1][0], Ar1, 5, 0); RD_A(fa[1][1], Ar1, 5, 1);
    RD_A(fa[2][0], Ar1, 6, 0); RD_A(fa[2][1], Ar1, 6, 1);
    RD_A(fa[3][0], Ar1, 7, 0); RD_A(fa[3][1], Ar1, 7, 1);
    STAGE(rowB0 +   0, kn2, Bs + 2 * 8192);
    PHASE_MID; MFMA16(4, 0, fa, fb0); PHASE_END;
    // ---- P8 (gate)
    STAGE(rowB0 + 128, kn2, Bs + 3 * 8192);
    PHASE_MID; MFMA16(4, 2, fa, fb2); PHASE_END_V4;
  }

  // ---- epilogue: overlay reductions into staging LDS ----
  __syncthreads();
  float* fo = (float*)lds;
  int* lab = (int*)(fo + 3072);   // labR[256] | labC[256]
  if (tid < 256) lab[tid] = labels[rowA0 + tid];
  else           lab[tid] = labels[rowB0 + (tid - 256)];
  __syncthreads();

  float ecol[4] = {}, pcol[4] = {};
  int lc[4];
  #pragma unroll
  for (int n = 0; n < 4; ++n) lc[n] = lab[256 + wn * 64 + n * 16 + l15];

  #pragma unroll
  for (int m = 0; m < 8; ++m) {
    #pragma unroll
    for (int r = 0; r < 4; ++r) {
      int rowl = wm * 128 + m * 16 + ((lane >> 4) << 2) + r;
      int lrv = lab[rowl];
      float e = 0.0f, p = 0.0f;
      #pragma unroll
      for (int n = 0; n < 4; ++n) {
        float s = acc[m][n][r] * INVT;
        float ex = __expf(s);
        float pm = (lrv == lc[n]) ? s : 0.0f;
        e += ex; p += pm; ecol[n] += ex; pcol[n] += pm;
      }
      #pragma unroll
      for (int msk = 1; msk < 16; msk <<= 1) {
        e += __shfl_xor(e, msk); p += __shfl_xor(p, msk);
      }
      if (l15 == 0) {
        fo[wn * 256 + rowl] = e;
        fo[1024 + wn * 256 + rowl] = p;
      }
    }
  }
  if (offdiag) {
    #pragma unroll
    for (int n = 0; n < 4; ++n) {
      float e = ecol[n], p = pcol[n];
      e += __shfl_xor(e, 16); e += __shfl_xor(e, 32);
      p += __shfl_xor(p, 16); p += __shfl_xor(p, 32);
      if (lane < 16) {
        int c = wn * 64 + n * 16 + l15;
        fo[2048 + wm * 256 + c] = e;
        fo[2560 + wm * 256 + c] = p;
      }
    }
  }
  __syncthreads();
  if (tid < 256) {
    float e = fo[tid] + fo[256 + tid] + fo[512 + tid] + fo[768 + tid];
    float p = fo[1024 + tid] + fo[1280 + tid] + fo[1536 + tid] + fo[1792 + tid];
    size_t off = (size_t)bx * N + rowA0 + tid;
    part_e[off] = e; part_p[off] = p;
  } else if (offdiag) {
    int c = tid - 256;
    float e = fo[2048 + c] + fo[2304 + c];
    float p = fo[2560 + c] + fo[2816 + c];
    size_t off = (size_t)by * N + rowB0 + c;
    part_e[off] = e; part_p[off] = p;
  }
}

// ---------------- kernel 4: per-row loss + atomic mean ----------------
__global__ __launch_bounds__(256) void k_final(
    const float* __restrict__ part_e, const float* __restrict__ part_p,
    const int* __restrict__ labels, const int* __restrict__ hist,
    float* __restrict__ out) {
  const int i = blockIdx.x * 256 + threadIdx.x;
  float e = 0.0f, p = 0.0f;
  #pragma unroll 8
  for (int cb = 0; cb < NCB; ++cb) {
    e += part_e[(size_t)cb * N + i];
    p += part_p[(size_t)cb * N + i];
  }
  float cnt = (float)hist[labels[i]];
  float li = logf(e) - p / cnt;
  #pragma unroll
  for (int m = 1; m < 64; m <<= 1) li += __shfl_xor(li, m);
  __shared__ float red[4];
  if ((threadIdx.x & 63) == 0) red[threadIdx.x >> 6] = li;
  __syncthreads();
  if (threadIdx.x == 0)
    atomicAdd(out, (red[0] + red[1] + red[2] + red[3]) * (1.0f / (float)N));
}

extern "C" void kernel_launch(void* const* d_in, const int* in_sizes, int n_in,
                              void* d_out, int out_size, void* d_ws, size_t ws_size,
                              hipStream_t stream) {
  const float* x = (const float*)d_in[0];
  const int* labels = (const int*)d_in[1];
  float* out = (float*)d_out;
  char* ws = (char*)d_ws;

  unsigned short* fb = (unsigned short*)ws;                 // 8 MB bf16 normalized
  float* part_e = (float*)(ws + (size_t)8 * 1024 * 1024);   // 1 MB (32 x 8192)
  float* part_p = (float*)(ws + (size_t)9 * 1024 * 1024);   // 1 MB
  int*   hist   = (int*)  (ws + (size_t)10 * 1024 * 1024);  // 512 B

  hipMemsetAsync(hist, 0, 512, stream);
  hipMemsetAsync(out, 0, sizeof(float), stream);
  k_normalize<<<N / 4, 256, 0, stream>>>(x, fb);
  k_hist<<<N / 256, 256, 0, stream>>>(labels, hist);
  k_gemm<<<NTRI, 512, 0, stream>>>(fb, labels, part_e, part_p);
  k_final<<<N / 256, 256, 0, stream>>>(part_e, part_p, labels, hist, out);
}

// Round 5
// 98.113 us; speedup vs baseline: 1.0372x; 1.0372x over previous
//
#include <hip/hip_runtime.h>
#include <hip/hip_bf16.h>

#define N 8192
#define D 512
#define BT 256          // tile: BM = BN = 256
#define BK 64
#define NCB (N / BT)    // 32 column blocks
#define NKT (D / BK)    // 8 K tiles
#define NTRI (NCB * (NCB + 1) / 2)  // 528 upper-triangle blocks
#define INVT 14.285714285714286f

typedef __attribute__((ext_vector_type(8))) short bf16x8;
typedef __attribute__((ext_vector_type(4))) float f32x4;
typedef __attribute__((ext_vector_type(8))) unsigned short u16x8;

__device__ __forceinline__ unsigned short f2bf(float f) {
  __hip_bfloat16 h = __float2bfloat16(f);
  return *reinterpret_cast<unsigned short*>(&h);
}

// ---------------- kernel 1: L2-normalize rows, cast to bf16 ----------------
__global__ __launch_bounds__(256) void k_normalize(const float* __restrict__ x,
                                                   unsigned short* __restrict__ fb) {
  const int row = blockIdx.x * 4 + (threadIdx.x >> 6);
  const int lane = threadIdx.x & 63;
  const float* rp = x + (size_t)row * D + lane * 8;
  float4 v0 = *reinterpret_cast<const float4*>(rp);
  float4 v1 = *reinterpret_cast<const float4*>(rp + 4);
  float s = v0.x*v0.x + v0.y*v0.y + v0.z*v0.z + v0.w*v0.w
          + v1.x*v1.x + v1.y*v1.y + v1.z*v1.z + v1.w*v1.w;
  #pragma unroll
  for (int m = 1; m < 64; m <<= 1) s += __shfl_xor(s, m);
  float inv = 1.0f / fmaxf(sqrtf(s), 1e-12f);
  u16x8 o;
  o[0] = f2bf(v0.x*inv); o[1] = f2bf(v0.y*inv); o[2] = f2bf(v0.z*inv); o[3] = f2bf(v0.w*inv);
  o[4] = f2bf(v1.x*inv); o[5] = f2bf(v1.y*inv); o[6] = f2bf(v1.z*inv); o[7] = f2bf(v1.w*inv);
  *reinterpret_cast<u16x8*>(fb + (size_t)row * D + lane * 8) = o;
}

// ---------------- kernel 2: label histogram (pos counts) ----------------
__global__ __launch_bounds__(256) void k_hist(const int* __restrict__ labels,
                                              int* __restrict__ hist) {
  __shared__ int h[128];
  int tid = threadIdx.x;
  if (tid < 128) h[tid] = 0;
  __syncthreads();
  int i = blockIdx.x * 256 + tid;
  atomicAdd(&h[labels[i]], 1);
  __syncthreads();
  if (tid < 128 && h[tid]) atomicAdd(&hist[tid], h[tid]);
}

// ---------------- kernel 3: 8-phase 256^2 fused GEMM + exp/mask reductions ----
// Same schedule as R4 (validated), but: K-loop fully unrolled (4 iters), all
// stage addresses from 4 per-thread base pointers + constant offsets, all
// ds_reads from 4 per-thread LDS vaddrs + offset: immediates. Goal: loop-live
// arch VGPRs <= 128 so acc[8][4] (128 AGPR) + arch fits the 256-unified/wave
// budget (1 block/CU, 2 waves/SIMD).  // R4 post-mortem: VGPR cap 128 + 17.6MB
// scratch writes = spills in MFMA loop -> MfmaUtil 16.5%.
#define GL16(g, dstbytes) __builtin_amdgcn_global_load_lds( \
    (const __attribute__((address_space(1))) unsigned int*)(g), \
    (__attribute__((address_space(3))) unsigned int*)((char*)lds + (dstbytes)), 16, 0, 0)

__global__ __launch_bounds__(512, 2) void k_gemm(
    const unsigned short* __restrict__ fb, const int* __restrict__ labels,
    float* __restrict__ part_e, float* __restrict__ part_p) {
  __shared__ __align__(16) short lds[65536];   // 128 KiB: A bytes [0,64K), B [64K,128K)

  const int tid = threadIdx.x;
  const int lane = tid & 63;
  const int w = tid >> 6;
  const int wm = w >> 2, wn = w & 3;
  const int l15 = lane & 15;

  const int t = blockIdx.x;
  int bx = (int)((sqrtf(8.0f * (float)t + 1.0f) - 1.0f) * 0.5f);
  while ((bx + 1) * (bx + 2) / 2 <= t) ++bx;
  while (bx * (bx + 1) / 2 > t) --bx;
  const int by = t - bx * (bx + 1) / 2;
  const bool offdiag = (bx != by);
  const int rowA0 = by * BT, rowB0 = bx * BT;

  // ---- per-thread global stage pointers (source pre-swizzled k-slot) ----
  const int r0 = tid >> 3;                       // row within 64-row group
  const int sw = ((tid & 7) ^ (r0 & 7)) << 3;    // swizzled k element offset
  const unsigned short* pA0 = fb + (size_t)(rowA0 + r0) * D + sw;        // it=0
  const unsigned short* pA1 = fb + (size_t)(rowA0 + 64 + r0) * D + sw;   // it=1
  const unsigned short* pB0 = fb + (size_t)(rowB0 + r0) * D + sw;
  const unsigned short* pB1 = fb + (size_t)(rowB0 + 64 + r0) * D + sw;

  // stage a full 128-row half: h in {0,1}, kt constant after unroll
#define STAGE_A(kt, h, DSTB) do { if ((kt) < NKT) { \
    GL16(pA0 + (h) * 128 * D + (kt) * BK, (DSTB) + w * 1024); \
    GL16(pA1 + (h) * 128 * D + (kt) * BK, (DSTB) + 8192 + w * 1024); } } while (0)
#define STAGE_B(kt, h, DSTB) do { if ((kt) < NKT) { \
    GL16(pB0 + (h) * 128 * D + (kt) * BK, (DSTB) + w * 1024); \
    GL16(pB1 + (h) * 128 * D + (kt) * BK, (DSTB) + 8192 + w * 1024); } } while (0)
  // LDS byte bases: A half(b,h) = (b*2+h)*16384 ; B half(b,h) = 65536 + (b*2+h)*16384

  // ---- per-thread LDS read vaddrs (ks = K-halfstep 0/1) ----
  const int hi16 = (lane >> 4) << 4;
  const int M = (l15 & 7) << 4;
  const char* ldsb = (const char*)lds;
  const char* vA_k0 = ldsb + wm * 16384 + l15 * 128 + ((0  + hi16) ^ M);
  const char* vA_k1 = ldsb + wm * 16384 + l15 * 128 + ((64 + hi16) ^ M);
  const char* vB_k0 = ldsb + 65536 + (wn >> 1) * 16384 + (wn & 1) * 8192 + l15 * 128 + ((0  + hi16) ^ M);
  const char* vB_k1 = ldsb + 65536 + (wn >> 1) * 16384 + (wn & 1) * 8192 + l15 * 128 + ((64 + hi16) ^ M);

#define RDA(dst, BUF, mloc, ks) \
    dst = *reinterpret_cast<const bf16x8*>(((ks) ? vA_k1 : vA_k0) + (BUF) * 32768 + (mloc) * 2048)
#define RDB(dst, BUF, nloc, ks) \
    dst = *reinterpret_cast<const bf16x8*>(((ks) ? vB_k1 : vB_k0) + (BUF) * 32768 + (nloc) * 2048)

  f32x4 acc[8][4] = {};

#define MFMA16(MB, NB, FA, FB) \
    _Pragma("unroll") for (int ks = 0; ks < 2; ++ks) \
    _Pragma("unroll") for (int mm = 0; mm < 4; ++mm) \
    _Pragma("unroll") for (int nn = 0; nn < 2; ++nn) \
      acc[(MB) + mm][(NB) + nn] = __builtin_amdgcn_mfma_f32_16x16x32_bf16( \
          FA[mm][ks], FB[nn][ks], acc[(MB) + mm][(NB) + nn], 0, 0, 0)

#define PHASE_MID do { __builtin_amdgcn_s_barrier(); \
    asm volatile("s_waitcnt lgkmcnt(0)" ::: "memory"); \
    __builtin_amdgcn_sched_barrier(0); \
    __builtin_amdgcn_s_setprio(1); } while (0)
#define PHASE_END do { __builtin_amdgcn_s_setprio(0); \
    __builtin_amdgcn_s_barrier(); } while (0)
#define PHASE_END_V4 do { __builtin_amdgcn_s_setprio(0); \
    asm volatile("s_waitcnt vmcnt(4)" ::: "memory"); \
    __builtin_amdgcn_s_barrier(); } while (0)
#define PHASE_END_V0 do { __builtin_amdgcn_s_setprio(0); \
    asm volatile("s_waitcnt vmcnt(0)" ::: "memory"); \
    __builtin_amdgcn_s_barrier(); } while (0)

  bf16x8 fa[4][2], fb0[2][2], fb2[2][2];

  // ---- prologue: K0 -> buf0 (B h0,h1, A h0,h1), K1.B -> buf1 ----
  STAGE_B(0, 0, 65536 + 0);
  STAGE_B(0, 1, 65536 + 16384);
  STAGE_A(0, 0, 0);
  STAGE_A(0, 1, 16384);
  STAGE_B(1, 0, 65536 + 32768);
  STAGE_B(1, 1, 65536 + 49152);
  asm volatile("s_waitcnt vmcnt(4)" ::: "memory");
  __builtin_amdgcn_s_barrier();

  // iter(kb, kn, kn2): P1-P4 compute buf0 (K-tile 2i), P5-P8 buf1 (2i+1).
  // stages: P1/P2 kb.A->buf1, P3/P4 kn.B->buf0, P5/P6 kn.A->buf0, P7/P8 kn2.B->buf1
#define ITERX(kb, kn, kn2, G4, G8) do { \
    RDA(fa[0][0], 0, 0, 0); RDA(fa[0][1], 0, 0, 1); \
    RDA(fa[1][0], 0, 1, 0); RDA(fa[1][1], 0, 1, 1); \
    RDA(fa[2][0], 0, 2, 0); RDA(fa[2][1], 0, 2, 1); \
    RDA(fa[3][0], 0, 3, 0); RDA(fa[3][1], 0, 3, 1); \
    RDB(fb0[0][0], 0, 0, 0); RDB(fb0[0][1], 0, 0, 1); \
    RDB(fb0[1][0], 0, 1, 0); RDB(fb0[1][1], 0, 1, 1); \
    STAGE_A(kb, 0, 32768); \
    PHASE_MID; MFMA16(0, 0, fa, fb0); PHASE_END; \
    RDB(fb2[0][0], 0, 2, 0); RDB(fb2[0][1], 0, 2, 1); \
    RDB(fb2[1][0], 0, 3, 0); RDB(fb2[1][1], 0, 3, 1); \
    STAGE_A(kb, 1, 49152); \
    PHASE_MID; MFMA16(0, 2, fa, fb2); PHASE_END; \
    RDA(fa[0][0], 0, 4, 0); RDA(fa[0][1], 0, 4, 1); \
    RDA(fa[1][0], 0, 5, 0); RDA(fa[1][1], 0, 5, 1); \
    RDA(fa[2][0], 0, 6, 0); RDA(fa[2][1], 0, 6, 1); \
    RDA(fa[3][0], 0, 7, 0); RDA(fa[3][1], 0, 7, 1); \
    STAGE_B(kn, 0, 65536 + 0); \
    PHASE_MID; MFMA16(4, 0, fa, fb0); PHASE_END; \
    STAGE_B(kn, 1, 65536 + 16384); \
    PHASE_MID; MFMA16(4, 2, fa, fb2); G4; \
    RDA(fa[0][0], 1, 0, 0); RDA(fa[0][1], 1, 0, 1); \
    RDA(fa[1][0], 1, 1, 0); RDA(fa[1][1], 1, 1, 1); \
    RDA(fa[2][0], 1, 2, 0); RDA(fa[2][1], 1, 2, 1); \
    RDA(fa[3][0], 1, 3, 0); RDA(fa[3][1], 1, 3, 1); \
    RDB(fb0[0][0], 1, 0, 0); RDB(fb0[0][1], 1, 0, 1); \
    RDB(fb0[1][0], 1, 1, 0); RDB(fb0[1][1], 1, 1, 1); \
    STAGE_A(kn, 0, 0); \
    PHASE_MID; MFMA16(0, 0, fa, fb0); PHASE_END; \
    RDB(fb2[0][0], 1, 2, 0); RDB(fb2[0][1], 1, 2, 1); \
    RDB(fb2[1][0], 1, 3, 0); RDB(fb2[1][1], 1, 3, 1); \
    STAGE_A(kn, 1, 16384); \
    PHASE_MID; MFMA16(0, 2, fa, fb2); PHASE_END; \
    RDA(fa[0][0], 1, 4, 0); RDA(fa[0][1], 1, 4, 1); \
    RDA(fa[1][0], 1, 5, 0); RDA(fa[1][1], 1, 5, 1); \
    RDA(fa[2][0], 1, 6, 0); RDA(fa[2][1], 1, 6, 1); \
    RDA(fa[3][0], 1, 7, 0); RDA(fa[3][1], 1, 7, 1); \
    STAGE_B(kn2, 0, 65536 + 32768); \
    PHASE_MID; MFMA16(4, 0, fa, fb0); PHASE_END; \
    STAGE_B(kn2, 1, 65536 + 49152); \
    PHASE_MID; MFMA16(4, 2, fa, fb2); G8; \
  } while (0)

  ITERX(1, 2, 3, PHASE_END_V4, PHASE_END_V4);
  ITERX(3, 4, 5, PHASE_END_V4, PHASE_END_V4);
  ITERX(5, 6, 7, PHASE_END_V4, PHASE_END_V4);
  ITERX(7, 8, 9, PHASE_END_V0, PHASE_END);

  // ---- epilogue: overlay reductions into staging LDS ----
  __syncthreads();
  float* fo = (float*)lds;
  int* lab = (int*)(fo + 3072);   // labR[256] | labC[256]
  if (tid < 256) lab[tid] = labels[rowA0 + tid];
  else           lab[tid] = labels[rowB0 + (tid - 256)];
  __syncthreads();

  float ecol[4] = {}, pcol[4] = {};
  int lc[4];
  #pragma unroll
  for (int n = 0; n < 4; ++n) lc[n] = lab[256 + wn * 64 + n * 16 + l15];

  #pragma unroll
  for (int m = 0; m < 8; ++m) {
    #pragma unroll
    for (int r = 0; r < 4; ++r) {
      int rowl = wm * 128 + m * 16 + ((lane >> 4) << 2) + r;
      int lrv = lab[rowl];
      float e = 0.0f, p = 0.0f;
      #pragma unroll
      for (int n = 0; n < 4; ++n) {
        float s = acc[m][n][r] * INVT;
        float ex = __expf(s);
        float pm = (lrv == lc[n]) ? s : 0.0f;
        e += ex; p += pm; ecol[n] += ex; pcol[n] += pm;
      }
      #pragma unroll
      for (int msk = 1; msk < 16; msk <<= 1) {
        e += __shfl_xor(e, msk); p += __shfl_xor(p, msk);
      }
      if (l15 == 0) {
        fo[wn * 256 + rowl] = e;
        fo[1024 + wn * 256 + rowl] = p;
      }
    }
  }
  if (offdiag) {
    #pragma unroll
    for (int n = 0; n < 4; ++n) {
      float e = ecol[n], p = pcol[n];
      e += __shfl_xor(e, 16); e += __shfl_xor(e, 32);
      p += __shfl_xor(p, 16); p += __shfl_xor(p, 32);
      if (lane < 16) {
        int c = wn * 64 + n * 16 + l15;
        fo[2048 + wm * 256 + c] = e;
        fo[2560 + wm * 256 + c] = p;
      }
    }
  }
  __syncthreads();
  if (tid < 256) {
    float e = fo[tid] + fo[256 + tid] + fo[512 + tid] + fo[768 + tid];
    float p = fo[1024 + tid] + fo[1280 + tid] + fo[1536 + tid] + fo[1792 + tid];
    size_t off = (size_t)bx * N + rowA0 + tid;
    part_e[off] = e; part_p[off] = p;
  } else if (offdiag) {
    int c = tid - 256;
    float e = fo[2048 + c] + fo[2304 + c];
    float p = fo[2560 + c] + fo[2816 + c];
    size_t off = (size_t)by * N + rowB0 + c;
    part_e[off] = e; part_p[off] = p;
  }
}

// ---------------- kernel 4: per-row loss + atomic mean ----------------
__global__ __launch_bounds__(256) void k_final(
    const float* __restrict__ part_e, const float* __restrict__ part_p,
    const int* __restrict__ labels, const int* __restrict__ hist,
    float* __restrict__ out) {
  const int i = blockIdx.x * 256 + threadIdx.x;
  float e = 0.0f, p = 0.0f;
  #pragma unroll 8
  for (int cb = 0; cb < NCB; ++cb) {
    e += part_e[(size_t)cb * N + i];
    p += part_p[(size_t)cb * N + i];
  }
  float cnt = (float)hist[labels[i]];
  float li = logf(e) - p / cnt;
  #pragma unroll
  for (int m = 1; m < 64; m <<= 1) li += __shfl_xor(li, m);
  __shared__ float red[4];
  if ((threadIdx.x & 63) == 0) red[threadIdx.x >> 6] = li;
  __syncthreads();
  if (threadIdx.x == 0)
    atomicAdd(out, (red[0] + red[1] + red[2] + red[3]) * (1.0f / (float)N));
}

extern "C" void kernel_launch(void* const* d_in, const int* in_sizes, int n_in,
                              void* d_out, int out_size, void* d_ws, size_t ws_size,
                              hipStream_t stream) {
  const float* x = (const float*)d_in[0];
  const int* labels = (const int*)d_in[1];
  float* out = (float*)d_out;
  char* ws = (char*)d_ws;

  unsigned short* fb = (unsigned short*)ws;                 // 8 MB bf16 normalized
  float* part_e = (float*)(ws + (size_t)8 * 1024 * 1024);   // 1 MB (32 x 8192)
  float* part_p = (float*)(ws + (size_t)9 * 1024 * 1024);   // 1 MB
  int*   hist   = (int*)  (ws + (size_t)10 * 1024 * 1024);  // 512 B

  hipMemsetAsync(hist, 0, 512, stream);
  hipMemsetAsync(out, 0, sizeof(float), stream);
  k_normalize<<<N / 4, 256, 0, stream>>>(x, fb);
  k_hist<<<N / 256, 256, 0, stream>>>(labels, hist);
  k_gemm<<<NTRI, 512, 0, stream>>>(fb, labels, part_e, part_p);
  k_final<<<N / 256, 256, 0, stream>>>(part_e, part_p, labels, hist, out);
}